// Round 7
// baseline (551.461 us; speedup 1.0000x reference)
//
#include <hip/hip_runtime.h>

#define TT 1024
#define LOG2E 1.4426950408889634f
#define LN2   0.6931471805599453f

typedef __attribute__((ext_vector_type(2))) float f32x2;
typedef __attribute__((ext_vector_type(4))) float f32x4;
typedef __attribute__((ext_vector_type(2))) _Float16 half2_t;
typedef __attribute__((ext_vector_type(4))) _Float16 half4;
typedef __attribute__((ext_vector_type(2))) unsigned int uint32x2;

#if __has_builtin(__builtin_amdgcn_exp2f)
#define EXP2F(x) __builtin_amdgcn_exp2f(x)
#else
#define EXP2F(x) exp2f(x)
#endif
#if __has_builtin(__builtin_amdgcn_logf)
#define LOG2F(x) __builtin_amdgcn_logf(x)
#else
#define LOG2F(x) log2f(x)
#endif
#define RCPF(x) __builtin_amdgcn_rcpf(x)

// Gates computed TRANSPOSED via v_mfma_f32_16x16x16f16 (D layout == B layout:
// updated h feeds the next step's B fragment directly — no LDS in recurrence).
// Gate domain pre-scaled into exp2 space; full-rate fp32 packed pairwise;
// transcendentals scalar (no packed trans pipe).
//
// Round-12 (R6: rcp-pairing on both paths = −0.9%; busy dropped ~30cy/SIMD-step
// but wall didn't follow → issue savings became idle → margin is chain-latency
// exposed, not issue-starved). Split the difference:
//  - KEEP c-path paired rcp (off the critical chain — R6's win).
//  - UNPAIR the tail rcp: the D2pr pairing put rcp->mul->mul serialization on
//    the h->hfrag->next-MFMA critical chain (~18cy/step). Back to independent
//    per-half rcp: ec -> D2 -> rcp -> mul -> cvt. Costs +2 quarter-rate rcp
//    of issue, which the latency-exposed margin absorbs.
// Occupancy is hard-capped at 2 waves/SIMD (batch 32768 / 16-per-wave = 2048
// waves on 1024 SIMDs); trans count is the algebraic minimum (5 exp/elem).
__global__ __launch_bounds__(256, 2)
void lstm_head_kernel(const float* __restrict__ x,
                      const float* __restrict__ W_ih,
                      const float* __restrict__ W_hh,
                      const float* __restrict__ b_ih,
                      const float* __restrict__ b_hh,
                      const float* __restrict__ W1,
                      const float* __restrict__ b1,
                      const float* __restrict__ W2,
                      const float* __restrict__ b2,
                      float* __restrict__ out)
{
    __shared__ float lds_f[4][16 * 17];   // final h fp32 staging for the head

    const int tid  = threadIdx.x;
    const int wib  = tid >> 6;
    const int lane = tid & 63;
    const int n    = lane & 15;           // batch within tile (and A-row m)
    const int q    = lane >> 4;           // quadrant
    const int batch0 = (blockIdx.x * 4 + wib) * 16;

    const float KG = 2.0f * LOG2E;        // g-gate / cell-domain scale

    // ---- fixed per-lane constants (pre-scaled into exp2 domain) ----
    half4 wfrag[4];        // A fragments: scaled W_hh rows g*16 + n, k = q*4+i
    f32x2 wih[4][2];       // scaled W_ih, row-pairs (r0,r1) / (r2,r3)
    f32x2 bias[4][2];      // scaled (b_ih + b_hh)
    #pragma unroll
    for (int g = 0; g < 4; ++g) {
        const float sc = (g == 2) ? KG : -LOG2E;   // i,f,o -> -log2e; g -> +2log2e
        const int arow = g * 16 + n;               // A: m = lane&15
        half4 wf;
        #pragma unroll
        for (int i = 0; i < 4; ++i)
            wf[i] = (_Float16)(W_hh[arow * 16 + (q * 4 + i)] * sc);
        wfrag[g] = wf;
        #pragma unroll
        for (int p = 0; p < 2; ++p) {
            const int row0 = g * 16 + q * 4 + 2 * p;
            wih[g][p]  = (f32x2){W_ih[row0] * sc, W_ih[row0 + 1] * sc};
            bias[g][p] = (f32x2){(b_ih[row0] + b_hh[row0]) * sc,
                                 (b_ih[row0 + 1] + b_hh[row0 + 1]) * sc};
        }
    }

    half4 hfrag = {(_Float16)0.f, (_Float16)0.f, (_Float16)0.f, (_Float16)0.f};
    f32x2 Cs[2] = {(f32x2){0.f, 0.f}, (f32x2){0.f, 0.f}};   // scaled cell state
    f32x2 hv[2] = {(f32x2){0.f, 0.f}, (f32x2){0.f, 0.f}};   // last h (fp32)

    const float* xp = x + (size_t)(batch0 + n) * TT;   // quads read same addr (broadcast)

    // prologue: first tile loaded up front; loop prefetches one t4 ahead
    float4 xv = *(const float4*)(xp);

    for (int t4 = 0; t4 < TT; t4 += 4) {
        const int tnext = (t4 + 4) & (TT - 1);          // wraps to 0 on last iter (dead)
        const float4 xv_pref = *(const float4*)(xp + tnext);

        const float xs4[4] = {xv.x, xv.y, xv.z, xv.w};

        #pragma unroll
        for (int s = 0; s < 4; ++s) {
            const float xs = xs4[s];

            // x-projection: xs-only, non-critical — prio 0 (pre-emption fodder)
            f32x4 ci[4];
            #pragma unroll
            for (int g = 0; g < 4; ++g) {
                const f32x2 c0 = __builtin_elementwise_fma(wih[g][0], (f32x2)xs, bias[g][0]);
                const f32x2 c1 = __builtin_elementwise_fma(wih[g][1], (f32x2)xs, bias[g][1]);
                ci[g] = (f32x4){c0.x, c0.y, c1.x, c1.y};
            }

            // critical head: MFMA issue + first dependent use
            f32x4 acc[4];
            __builtin_amdgcn_s_setprio(1);
            #pragma unroll
            for (int g = 0; g < 4; ++g)
                acc[g] = __builtin_amdgcn_mfma_f32_16x16x16f16(wfrag[g], hfrag, ci[g], 0, 0, 0);
            __builtin_amdgcn_s_setprio(0);

            // bulk c-update (prio 0): gates -> exps -> D,num per half
            f32x2 eo_[2], Dv[2], numv[2];
            #pragma unroll
            for (int p = 0; p < 2; ++p) {
                const f32x2 ai = {acc[0][2*p], acc[0][2*p + 1]};
                const f32x2 af = {acc[1][2*p], acc[1][2*p + 1]};
                const f32x2 ag = {acc[2][2*p], acc[2][2*p + 1]};
                const f32x2 ao = {acc[3][2*p], acc[3][2*p + 1]};

                const f32x2 ei = {EXP2F(ai.x), EXP2F(ai.y)};
                const f32x2 ef = {EXP2F(af.x), EXP2F(af.y)};
                const f32x2 eg = {EXP2F(ag.x), EXP2F(ag.y)};
                eo_[p] = (f32x2){EXP2F(ao.x), EXP2F(ao.y)};

                // c' = c/(1+ef) + (eg-1)/((1+ei)(eg+1))  [scaled by KG]
                const f32x2 egp = eg + 1.0f;
                const f32x2 egm = __builtin_elementwise_fma((f32x2)KG, eg, (f32x2)(-KG));
                const f32x2 P   = __builtin_elementwise_fma(ei, egp, egp);   // (1+ei)(eg+1)
                Dv[p]           = __builtin_elementwise_fma(ef, P, P);       // (1+ef)*P
                const f32x2 t2  = __builtin_elementwise_fma(ef, egm, egm);   // (1+ef)*egm
                numv[p]         = __builtin_elementwise_fma(Cs[p], P, t2);
            }
            // paired reciprocal across halves for the c-path (off-critical):
            // rp = rcp(D0*D1); 1/D0 = D1*rp; 1/D1 = D0*rp
            {
                const f32x2 Dpr = Dv[0] * Dv[1];
                const f32x2 rp  = {RCPF(Dpr.x), RCPF(Dpr.y)};
                Cs[0] = numv[0] * (Dv[1] * rp);
                Cs[1] = numv[1] * (Dv[0] * rp);
            }

            // critical tail (prio 1): ec -> h -> cvt -> hfrag feeds next MFMA.
            // UNPAIRED rcp here — shortest possible chain to hfrag.
            __builtin_amdgcn_s_setprio(1);
            unsigned int hb[2];
            #pragma unroll
            for (int p = 0; p < 2; ++p) {
                const f32x2 Cn  = Cs[p];
                const f32x2 ec  = {EXP2F(Cn.x), EXP2F(Cn.y)};
                const f32x2 ecp = ec + 1.0f;
                const f32x2 ecm = ec - 1.0f;
                const f32x2 D2  = __builtin_elementwise_fma(eo_[p], ecp, ecp); // (1+eo)(ec+1)
                const f32x2 rD2 = {RCPF(D2.x), RCPF(D2.y)};
                const f32x2 h2  = ecm * rD2;
                hv[p] = h2;
                hb[p] = __builtin_bit_cast(unsigned int,
                            __builtin_amdgcn_cvt_pkrtz(h2.x, h2.y));
            }
            hfrag = __builtin_bit_cast(half4, (uint32x2){hb[0], hb[1]});
            __builtin_amdgcn_s_setprio(0);
        }

        xv = xv_pref;   // rotate: prefetched tile becomes current
    }

    // ---- head: stage final h (fp32) -> 16 lanes do MLP + log_softmax ----
    float* fh = lds_f[wib];
    #pragma unroll
    for (int p = 0; p < 2; ++p) {
        fh[n * 17 + (q * 4 + 2*p)]     = hv[p].x;
        fh[n * 17 + (q * 4 + 2*p + 1)] = hv[p].y;
    }

    if (lane < 16) {
        const int b = batch0 + lane;
        float hvv[16];
        #pragma unroll
        for (int j = 0; j < 16; ++j) hvv[j] = fh[lane * 17 + j];

        float a1[32];
        #pragma unroll
        for (int u = 0; u < 32; ++u) {
            float s = b1[u];
            #pragma unroll
            for (int j = 0; j < 16; ++j) s = fmaf(W1[u * 16 + j], hvv[j], s);
            a1[u] = fmaxf(s, 0.0f);
        }

        float z[6];
        float m = -1e30f;
        #pragma unroll
        for (int v = 0; v < 6; ++v) {
            float s = b2[v];
            #pragma unroll
            for (int u = 0; u < 32; ++u) s = fmaf(W2[v * 32 + u], a1[u], s);
            z[v] = s;
            m = fmaxf(m, s);
        }
        float se = 0.0f;
        #pragma unroll
        for (int v = 0; v < 6; ++v) se += EXP2F((z[v] - m) * LOG2E);
        const float lse = m + LOG2F(se) * LN2;
        #pragma unroll
        for (int v = 0; v < 6; ++v) out[b * 6 + v] = z[v] - lse;
    }
}

extern "C" void kernel_launch(void* const* d_in, const int* in_sizes, int n_in,
                              void* d_out, int out_size, void* d_ws, size_t ws_size,
                              hipStream_t stream) {
    const float* x    = (const float*)d_in[0];
    const float* W_ih = (const float*)d_in[1];
    const float* W_hh = (const float*)d_in[2];
    const float* b_ih = (const float*)d_in[3];
    const float* b_hh = (const float*)d_in[4];
    const float* W1   = (const float*)d_in[5];
    const float* b1   = (const float*)d_in[6];
    const float* W2   = (const float*)d_in[7];
    const float* b2   = (const float*)d_in[8];
    float* out = (float*)d_out;

    const int B = out_size / 6;          // 32768
    const int nblocks = B / 64;          // 64 batch per block (4 waves x 16)

    hipLaunchKernelGGL(lstm_head_kernel, dim3(nblocks), dim3(256), 0, stream,
                       x, W_ih, W_hh, b_ih, b_hh, W1, b1, W2, b2, out);
}

// Round 8
// 547.810 us; speedup vs baseline: 1.0067x; 1.0067x over previous
//
#include <hip/hip_runtime.h>

#define TT 1024
#define LOG2E 1.4426950408889634f
#define LN2   0.6931471805599453f

typedef __attribute__((ext_vector_type(2))) float f32x2;
typedef __attribute__((ext_vector_type(4))) float f32x4;
typedef __attribute__((ext_vector_type(2))) _Float16 half2_t;
typedef __attribute__((ext_vector_type(4))) _Float16 half4;
typedef __attribute__((ext_vector_type(2))) unsigned int uint32x2;

#if __has_builtin(__builtin_amdgcn_exp2f)
#define EXP2F(x) __builtin_amdgcn_exp2f(x)
#else
#define EXP2F(x) exp2f(x)
#endif
#if __has_builtin(__builtin_amdgcn_logf)
#define LOG2F(x) __builtin_amdgcn_logf(x)
#else
#define LOG2F(x) log2f(x)
#endif
#define RCPF(x) __builtin_amdgcn_rcpf(x)

// FINAL (best measured: 457µs rocprof, R6 configuration restored after R7's
// tail-unpair regressed 1%).
//
// Structure: gates computed TRANSPOSED via v_mfma_f32_16x16x16f16 (D layout
// == B layout: updated h feeds the next step's B fragment directly — no LDS
// in the recurrence). Gate domain pre-scaled into exp2 space; (1+e)*y folded
// as fma(e,y,y); reciprocals PAIRED across the two independent p-halves
// (rp = rcp(D0*D1); 1/D0 = D1*rp) on both the cell and h paths — 24 trans
// ops/step total. Full-rate fp32 packed pairwise (v_pk_*_f32); trans scalar.
// s_setprio(1) wraps the two critical windows (MFMA issue; ec->h->cvt->hfrag
// tail) so the wave in its serial window pre-empts its partner's bulk work.
//
// Measured falsifications (do not revisit): deeper prefetch (neutral);
// 2-tile/1-wave static ILP (−45%, compiler serializes); tail rcp unpair
// (−1%). Port occupancy at final: VALU 77% + MFMA 13% ≈ 90%; occupancy
// hard-capped at 2 waves/SIMD by the 16-batch/wave MFMA tiling.
__global__ __launch_bounds__(256, 2)
void lstm_head_kernel(const float* __restrict__ x,
                      const float* __restrict__ W_ih,
                      const float* __restrict__ W_hh,
                      const float* __restrict__ b_ih,
                      const float* __restrict__ b_hh,
                      const float* __restrict__ W1,
                      const float* __restrict__ b1,
                      const float* __restrict__ W2,
                      const float* __restrict__ b2,
                      float* __restrict__ out)
{
    __shared__ float lds_f[4][16 * 17];   // final h fp32 staging for the head

    const int tid  = threadIdx.x;
    const int wib  = tid >> 6;
    const int lane = tid & 63;
    const int n    = lane & 15;           // batch within tile (and A-row m)
    const int q    = lane >> 4;           // quadrant
    const int batch0 = (blockIdx.x * 4 + wib) * 16;

    const float KG = 2.0f * LOG2E;        // g-gate / cell-domain scale

    // ---- fixed per-lane constants (pre-scaled into exp2 domain) ----
    half4 wfrag[4];        // A fragments: scaled W_hh rows g*16 + n, k = q*4+i
    f32x2 wih[4][2];       // scaled W_ih, row-pairs (r0,r1) / (r2,r3)
    f32x2 bias[4][2];      // scaled (b_ih + b_hh)
    #pragma unroll
    for (int g = 0; g < 4; ++g) {
        const float sc = (g == 2) ? KG : -LOG2E;   // i,f,o -> -log2e; g -> +2log2e
        const int arow = g * 16 + n;               // A: m = lane&15
        half4 wf;
        #pragma unroll
        for (int i = 0; i < 4; ++i)
            wf[i] = (_Float16)(W_hh[arow * 16 + (q * 4 + i)] * sc);
        wfrag[g] = wf;
        #pragma unroll
        for (int p = 0; p < 2; ++p) {
            const int row0 = g * 16 + q * 4 + 2 * p;
            wih[g][p]  = (f32x2){W_ih[row0] * sc, W_ih[row0 + 1] * sc};
            bias[g][p] = (f32x2){(b_ih[row0] + b_hh[row0]) * sc,
                                 (b_ih[row0 + 1] + b_hh[row0 + 1]) * sc};
        }
    }

    half4 hfrag = {(_Float16)0.f, (_Float16)0.f, (_Float16)0.f, (_Float16)0.f};
    f32x2 Cs[2] = {(f32x2){0.f, 0.f}, (f32x2){0.f, 0.f}};   // scaled cell state
    f32x2 hv[2] = {(f32x2){0.f, 0.f}, (f32x2){0.f, 0.f}};   // last h (fp32)

    const float* xp = x + (size_t)(batch0 + n) * TT;   // quads read same addr (broadcast)

    // prologue: first tile loaded up front; loop prefetches one t4 ahead
    float4 xv = *(const float4*)(xp);

    for (int t4 = 0; t4 < TT; t4 += 4) {
        const int tnext = (t4 + 4) & (TT - 1);          // wraps to 0 on last iter (dead)
        const float4 xv_pref = *(const float4*)(xp + tnext);

        const float xs4[4] = {xv.x, xv.y, xv.z, xv.w};

        #pragma unroll
        for (int s = 0; s < 4; ++s) {
            const float xs = xs4[s];

            // x-projection: xs-only, non-critical — prio 0 (pre-emption fodder)
            f32x4 ci[4];
            #pragma unroll
            for (int g = 0; g < 4; ++g) {
                const f32x2 c0 = __builtin_elementwise_fma(wih[g][0], (f32x2)xs, bias[g][0]);
                const f32x2 c1 = __builtin_elementwise_fma(wih[g][1], (f32x2)xs, bias[g][1]);
                ci[g] = (f32x4){c0.x, c0.y, c1.x, c1.y};
            }

            // critical head: MFMA issue + first dependent use
            f32x4 acc[4];
            __builtin_amdgcn_s_setprio(1);
            #pragma unroll
            for (int g = 0; g < 4; ++g)
                acc[g] = __builtin_amdgcn_mfma_f32_16x16x16f16(wfrag[g], hfrag, ci[g], 0, 0, 0);
            __builtin_amdgcn_s_setprio(0);

            // bulk c-update (prio 0): gates -> exps -> D,num per half
            f32x2 eo_[2], Dv[2], numv[2];
            #pragma unroll
            for (int p = 0; p < 2; ++p) {
                const f32x2 ai = {acc[0][2*p], acc[0][2*p + 1]};
                const f32x2 af = {acc[1][2*p], acc[1][2*p + 1]};
                const f32x2 ag = {acc[2][2*p], acc[2][2*p + 1]};
                const f32x2 ao = {acc[3][2*p], acc[3][2*p + 1]};

                const f32x2 ei = {EXP2F(ai.x), EXP2F(ai.y)};
                const f32x2 ef = {EXP2F(af.x), EXP2F(af.y)};
                const f32x2 eg = {EXP2F(ag.x), EXP2F(ag.y)};
                eo_[p] = (f32x2){EXP2F(ao.x), EXP2F(ao.y)};

                // c' = c/(1+ef) + (eg-1)/((1+ei)(eg+1))  [scaled by KG]
                const f32x2 egp = eg + 1.0f;
                const f32x2 egm = __builtin_elementwise_fma((f32x2)KG, eg, (f32x2)(-KG));
                const f32x2 P   = __builtin_elementwise_fma(ei, egp, egp);   // (1+ei)(eg+1)
                Dv[p]           = __builtin_elementwise_fma(ef, P, P);       // (1+ef)*P
                const f32x2 t2  = __builtin_elementwise_fma(ef, egm, egm);   // (1+ef)*egm
                numv[p]         = __builtin_elementwise_fma(Cs[p], P, t2);
            }
            // paired reciprocal across the two independent halves (2 rcp not 4)
            {
                const f32x2 Dpr = Dv[0] * Dv[1];
                const f32x2 rp  = {RCPF(Dpr.x), RCPF(Dpr.y)};
                Cs[0] = numv[0] * (Dv[1] * rp);
                Cs[1] = numv[1] * (Dv[0] * rp);
            }

            // critical tail (prio 1): ec -> h -> cvt -> hfrag feeds next MFMA
            __builtin_amdgcn_s_setprio(1);
            f32x2 ecm_[2], D2v[2];
            #pragma unroll
            for (int p = 0; p < 2; ++p) {
                const f32x2 Cn  = Cs[p];
                const f32x2 ec  = {EXP2F(Cn.x), EXP2F(Cn.y)};
                const f32x2 ecp = ec + 1.0f;
                ecm_[p]         = ec - 1.0f;
                D2v[p]          = __builtin_elementwise_fma(eo_[p], ecp, ecp); // (1+eo)(ec+1)
            }
            {
                const f32x2 D2pr = D2v[0] * D2v[1];
                const f32x2 rp2  = {RCPF(D2pr.x), RCPF(D2pr.y)};
                hv[0] = ecm_[0] * (D2v[1] * rp2);
                hv[1] = ecm_[1] * (D2v[0] * rp2);
            }
            const unsigned int hb0 =
                __builtin_bit_cast(unsigned int, __builtin_amdgcn_cvt_pkrtz(hv[0].x, hv[0].y));
            const unsigned int hb1 =
                __builtin_bit_cast(unsigned int, __builtin_amdgcn_cvt_pkrtz(hv[1].x, hv[1].y));
            hfrag = __builtin_bit_cast(half4, (uint32x2){hb0, hb1});
            __builtin_amdgcn_s_setprio(0);
        }

        xv = xv_pref;   // rotate: prefetched tile becomes current
    }

    // ---- head: stage final h (fp32) -> 16 lanes do MLP + log_softmax ----
    float* fh = lds_f[wib];
    #pragma unroll
    for (int p = 0; p < 2; ++p) {
        fh[n * 17 + (q * 4 + 2*p)]     = hv[p].x;
        fh[n * 17 + (q * 4 + 2*p + 1)] = hv[p].y;
    }

    if (lane < 16) {
        const int b = batch0 + lane;
        float hvv[16];
        #pragma unroll
        for (int j = 0; j < 16; ++j) hvv[j] = fh[lane * 17 + j];

        float a1[32];
        #pragma unroll
        for (int u = 0; u < 32; ++u) {
            float s = b1[u];
            #pragma unroll
            for (int j = 0; j < 16; ++j) s = fmaf(W1[u * 16 + j], hvv[j], s);
            a1[u] = fmaxf(s, 0.0f);
        }

        float z[6];
        float m = -1e30f;
        #pragma unroll
        for (int v = 0; v < 6; ++v) {
            float s = b2[v];
            #pragma unroll
            for (int u = 0; u < 32; ++u) s = fmaf(W2[v * 32 + u], a1[u], s);
            z[v] = s;
            m = fmaxf(m, s);
        }
        float se = 0.0f;
        #pragma unroll
        for (int v = 0; v < 6; ++v) se += EXP2F((z[v] - m) * LOG2E);
        const float lse = m + LOG2F(se) * LN2;
        #pragma unroll
        for (int v = 0; v < 6; ++v) out[b * 6 + v] = z[v] - lse;
    }
}

extern "C" void kernel_launch(void* const* d_in, const int* in_sizes, int n_in,
                              void* d_out, int out_size, void* d_ws, size_t ws_size,
                              hipStream_t stream) {
    const float* x    = (const float*)d_in[0];
    const float* W_ih = (const float*)d_in[1];
    const float* W_hh = (const float*)d_in[2];
    const float* b_ih = (const float*)d_in[3];
    const float* b_hh = (const float*)d_in[4];
    const float* W1   = (const float*)d_in[5];
    const float* b1   = (const float*)d_in[6];
    const float* W2   = (const float*)d_in[7];
    const float* b2   = (const float*)d_in[8];
    float* out = (float*)d_out;

    const int B = out_size / 6;          // 32768
    const int nblocks = B / 64;          // 64 batch per block (4 waves x 16)

    hipLaunchKernelGGL(lstm_head_kernel, dim3(nblocks), dim3(256), 0, stream,
                       x, W_ih, W_hh, b_ih, b_hh, W1, b1, W2, b2, out);
}